// Round 3
// baseline (610.924 us; speedup 1.0000x reference)
//
#include <hip/hip_runtime.h>

#define BB 32
#define TT 8
#define NN 1024
#define KNN 20
#define HH 64
#define CLS 14

__device__ __constant__ float kEPS = 1e-5f;

// Two independent ascending bitonic sorts (one u32 value per lane each),
// stages interleaved so the serial shuffle chains overlap.
__device__ __forceinline__ void bitonic64_u32x2(unsigned& a, unsigned& b, int lane) {
    #pragma unroll
    for (int k = 2; k <= 64; k <<= 1) {
        #pragma unroll
        for (int j = k >> 1; j >= 1; j >>= 1) {
            const bool keepmin = (((lane & k) == 0) == ((lane & j) == 0));
            const unsigned oa = __shfl_xor(a, j, 64);
            const unsigned ob = __shfl_xor(b, j, 64);
            const unsigned mna = min(a, oa), mxa = max(a, oa);
            const unsigned mnb = min(b, ob), mxb = max(b, ob);
            a = keepmin ? mna : mxa;
            b = keepmin ? mnb : mxb;
        }
    }
}

// Exact top-20 set selection among survivors (one survivor key per lane,
// lanes [0,base)). v20 = 20th-smallest flipped-dist among survivors.
// Set = {fd < v20} U (lowest-idx elements with fd == v20), matching jax
// top_k's (distance, lowest-index) lexicographic tie semantics.
__device__ __forceinline__ void select20(unsigned long long key, int base,
                                         unsigned v20, int lane,
                                         unsigned long long below,
                                         unsigned* nb) {
    const bool valid = lane < base;
    const unsigned fd  = valid ? (unsigned)(key >> 32) : 0xFFFFFFFFu;
    const unsigned idx = (unsigned)key & 1023u;
    const unsigned long long ltm = __ballot(valid && fd < v20);
    const int clt  = (int)__popcll(ltm);
    const int need = KNN - clt;
    const unsigned long long tiedm = __ballot(valid && fd == v20);
    const int nt = (int)__popcll(tiedm);
    bool sel;
    if (nt == need) {
        sel = valid && fd <= v20;
    } else {
        // rare: rank tied elements by index, keep the `need` smallest
        int r = 0;
        unsigned long long mm = tiedm;
        while (mm) {
            const int l = __builtin_ctzll(mm);
            const unsigned oi = __shfl(idx, l, 64);
            r += (oi < idx) ? 1 : 0;
            mm &= mm - 1;
        }
        sel = valid && (fd < v20 || (fd == v20 && r < need));
    }
    const unsigned long long sm = __ballot(sel);
    if (sel) nb[(int)__popcll(sm & below)] = idx;
}

// Exact iterative extraction fallback (survivor-buffer overflow only).
__device__ __forceinline__ void fallback20(unsigned fd[16], int lane, unsigned* nb) {
    for (int kk = 0; kk < KNN; ++kk) {
        unsigned bv = fd[0];
        int bi = 0;
        #pragma unroll
        for (int i = 1; i < 16; ++i)
            if (fd[i] < bv) { bv = fd[i]; bi = i; }
        unsigned bj = (unsigned)(bi * 64 + lane);
        #pragma unroll
        for (int off = 32; off >= 1; off >>= 1) {
            const unsigned ov = __shfl_xor(bv, off, 64);
            const unsigned oj = __shfl_xor(bj, off, 64);
            if (ov < bv || (ov == bv && oj < bj)) { bv = ov; bj = oj; }
        }
        if (lane == 0) nb[kk] = bj;
        #pragma unroll
        for (int i = 0; i < 16; ++i)
            if (bj == (unsigned)(i * 64 + lane)) fd[i] = 0xFFFFFFFFu;
    }
}

// ---------------------------------------------------------------------------
// Kernel A: per (t, b, 64-point chunk). One wave = 16 query points, processed
// 2 at a time (ILP). Per point: distances (flipped-uint) -> per-lane min ->
// 12-step ballot radix pivot (upper bound on d(20)) -> ballot-compact
// survivors to LDS -> interleaved u32 bitonic -> exact top-20 set -> EdgeConv
// MLP (lane = channel), clamp folded into running max, uint atomicMax to acc.
// ---------------------------------------------------------------------------
__global__ __launch_bounds__(256) void knn_edge_kernel(
    const float* __restrict__ x,    // [B,T,N,3]
    const float* __restrict__ W1,   // [6,H]
    const float* __restrict__ b1,   // [H]
    const float* __restrict__ g1,   // [H]
    const float* __restrict__ be1,  // [H]
    float* __restrict__ acc)        // [B, 7*H], zero-initialized
{
    __shared__ float4 pts[NN];                         // x, y, z, |p|^2
    __shared__ unsigned long long keybuf[4][2][64];    // per-wave, per-point
    __shared__ unsigned nbuf[4][2][KNN];
    __shared__ unsigned smax[HH];

    const int chunk = blockIdx.x;   // 0..15
    const int b     = blockIdx.y;   // 0..31
    const int t     = blockIdx.z;   // 0..6

    const int tid  = threadIdx.x;
    const int lane = tid & 63;
    const int wave = tid >> 6;

    for (int i = tid; i < NN; i += 256) {
        const float* p = x + (((size_t)b * TT + t) * NN + i) * 3;
        const float px = p[0], py = p[1], pz = p[2];
        pts[i] = make_float4(px, py, pz, px * px + py * py + pz * pz);
    }
    if (tid < HH) smax[tid] = 0u;
    __syncthreads();

    const float w0 = W1[0 * HH + lane], w1 = W1[1 * HH + lane],
                w2 = W1[2 * HH + lane], w3 = W1[3 * HH + lane],
                w4 = W1[4 * HH + lane], w5 = W1[5 * HH + lane];
    const float w03 = w0 - w3, w14 = w1 - w4, w25 = w2 - w5;
    const float b1l   = b1[lane];
    const float scale = g1[lane] / sqrtf(1.0f + kEPS);
    const float be1l  = be1[lane];

    const unsigned long long below = (1ull << lane) - 1ull;
    float cmax = 0.0f;

    const int n0 = chunk * 64 + wave * 16;
    for (int pp = 0; pp < 8; ++pp) {
        const int nA = n0 + 2 * pp;
        const float* c = x + (((size_t)b * TT + (t + 1)) * NN + nA) * 3;
        const float cxA = c[0], cyA = c[1], czA = c[2];
        const float cxB = c[3], cyB = c[4], czB = c[5];
        const float s1A = cxA * cxA + cyA * cyA + czA * czA;
        const float s1B = cxB * cxB + cyB * cyB + czB * czB;
        const float n2xA = -2.0f * cxA, n2yA = -2.0f * cyA, n2zA = -2.0f * czA;
        const float n2xB = -2.0f * cxB, n2yB = -2.0f * cyB, n2zB = -2.0f * czB;

        // distances (order-preserving flipped uint), shared LDS read
        unsigned fdA[16], fdB[16];
        unsigned mnA = 0xFFFFFFFFu, mnB = 0xFFFFFFFFu;
        #pragma unroll
        for (int i = 0; i < 16; ++i) {
            const float4 q = pts[i * 64 + lane];
            const float dA = fmaf(n2xA, q.x, fmaf(n2yA, q.y, fmaf(n2zA, q.z, s1A + q.w)));
            const float dB = fmaf(n2xB, q.x, fmaf(n2yB, q.y, fmaf(n2zB, q.z, s1B + q.w)));
            unsigned uA = __float_as_uint(dA);
            unsigned uB = __float_as_uint(dB);
            uA ^= (unsigned)((int)uA >> 31) | 0x80000000u;
            uB ^= (unsigned)((int)uB >> 31) | 0x80000000u;
            fdA[i] = uA; fdB[i] = uB;
            mnA = min(mnA, uA); mnB = min(mnB, uB);
        }

        // 12-step ballot radix: top-12 bits of the 20th-smallest lane-min.
        // UB = prefix|0xFFFFF >= 20th lane-min >= true d(20). No DS chain.
        unsigned pA = 0, pB = 0;
        int kA = 19, kB = 19;
        #pragma unroll
        for (int bit = 31; bit >= 20; --bit) {
            const unsigned long long zA = __ballot(((mnA ^ pA) >> bit) == 0u);
            const unsigned long long zB = __ballot(((mnB ^ pB) >> bit) == 0u);
            const int cA0 = (int)__popcll(zA);
            const int cB0 = (int)__popcll(zB);
            if (kA >= cA0) { pA |= (1u << bit); kA -= cA0; }
            if (kB >= cB0) { pB |= (1u << bit); kB -= cB0; }
        }
        const unsigned ubA = pA | 0xFFFFFu;
        const unsigned ubB = pB | 0xFFFFFu;

        // ballot-compact survivors into per-wave LDS key buffers
        int baseA = 0, baseB = 0;
        #pragma unroll
        for (int i = 0; i < 16; ++i) {
            const bool prA = fdA[i] <= ubA;
            const bool prB = fdB[i] <= ubB;
            const unsigned long long mA = __ballot(prA);
            const unsigned long long mB = __ballot(prB);
            if (prA) {
                const int pos = baseA + (int)__popcll(mA & below);
                if (pos < 64) keybuf[wave][0][pos] =
                    ((unsigned long long)fdA[i] << 32) | (unsigned)(i * 64 + lane);
            }
            if (prB) {
                const int pos = baseB + (int)__popcll(mB & below);
                if (pos < 64) keybuf[wave][1][pos] =
                    ((unsigned long long)fdB[i] << 32) | (unsigned)(i * 64 + lane);
            }
            baseA += (int)__popcll(mA);
            baseB += (int)__popcll(mB);
        }

        if (baseA <= 64 && baseB <= 64) {
            const unsigned long long keyA = keybuf[wave][0][lane];
            const unsigned long long keyB = keybuf[wave][1][lane];
            unsigned sA = (lane < baseA) ? (unsigned)(keyA >> 32) : 0xFFFFFFFFu;
            unsigned sB = (lane < baseB) ? (unsigned)(keyB >> 32) : 0xFFFFFFFFu;
            bitonic64_u32x2(sA, sB, lane);
            const unsigned v20A = __shfl(sA, 19, 64);
            const unsigned v20B = __shfl(sB, 19, 64);
            select20(keyA, baseA, v20A, lane, below, &nbuf[wave][0][0]);
            select20(keyB, baseB, v20B, lane, below, &nbuf[wave][1][0]);
        } else {
            // pathological clustering: exact fallback (fd arrays still live)
            fallback20(fdA, lane, &nbuf[wave][0][0]);
            fallback20(fdB, lane, &nbuf[wave][1][0]);
        }

        // EdgeConv MLP, lane = channel; algebra folded:
        // h = b + nx*w0+ny*w1+nz*w2 + (c-n)·(w3,w4,w5)
        //   = [b + c·(w3,w4,w5)] + n·(w0-w3, w1-w4, w2-w5)
        const float mbA = fmaf(cxA, w3, fmaf(cyA, w4, fmaf(czA, w5, b1l)));
        const float mbB = fmaf(cxB, w3, fmaf(cyB, w4, fmaf(czB, w5, b1l)));
        #pragma unroll
        for (int kk = 0; kk < KNN; ++kk) {
            const int jA = (int)nbuf[wave][0][kk];   // uniform -> broadcast
            const int jB = (int)nbuf[wave][1][kk];
            const float4 qA = pts[jA];
            const float4 qB = pts[jB];
            float hA = fmaf(qA.x, w03, fmaf(qA.y, w14, fmaf(qA.z, w25, mbA)));
            float hB = fmaf(qB.x, w03, fmaf(qB.y, w14, fmaf(qB.z, w25, mbB)));
            hA = fmaxf(hA, 0.0f);
            hB = fmaxf(hB, 0.0f);
            hA = fmaf(hA, scale, be1l);
            hB = fmaf(hB, scale, be1l);
            cmax = fmaxf(cmax, fmaxf(hA, hB));
        }
    }

    atomicMax(&smax[lane], __float_as_uint(cmax));
    __syncthreads();
    if (tid < HH) {
        unsigned* dst = (unsigned*)(acc + ((size_t)b * 448 + t * 64 + tid));
        atomicMax(dst, smax[tid]);
    }
}

// ---------------------------------------------------------------------------
// Kernel B: MLP head, one block (512 threads) per batch row.
// ---------------------------------------------------------------------------
__global__ __launch_bounds__(512) void head_kernel(
    const float* __restrict__ acc,  // [B,448]
    const float* __restrict__ Wa, const float* __restrict__ ba,
    const float* __restrict__ ga, const float* __restrict__ bea,
    const float* __restrict__ Wb, const float* __restrict__ bb,
    const float* __restrict__ gb, const float* __restrict__ beb,
    const float* __restrict__ Wc, const float* __restrict__ bc,
    float* __restrict__ out)        // [B,CLS]
{
    __shared__ float s0[448];
    __shared__ float h1[512];
    __shared__ float h2[256];
    __shared__ float lg[CLS];
    __shared__ float red[2];

    const int b   = blockIdx.x;
    const int tid = threadIdx.x;
    const float inv = 1.0f / sqrtf(1.0f + kEPS);

    if (tid < 448) s0[tid] = acc[(size_t)b * 448 + tid];
    __syncthreads();

    {   // layer a: 448 -> 512
        float s = ba[tid];
        for (int d = 0; d < 448; ++d) s = fmaf(s0[d], Wa[d * 512 + tid], s);
        s = fmaxf(s, 0.0f);
        h1[tid] = fmaf(s, ga[tid] * inv, bea[tid]);
    }
    __syncthreads();
    if (tid < 256) {  // layer b: 512 -> 256
        float s = bb[tid];
        for (int d = 0; d < 512; ++d) s = fmaf(h1[d], Wb[d * 256 + tid], s);
        s = fmaxf(s, 0.0f);
        h2[tid] = fmaf(s, gb[tid] * inv, beb[tid]);
    }
    __syncthreads();
    if (tid < CLS) {  // logits: 256 -> 14
        float s = bc[tid];
        for (int d = 0; d < 256; ++d) s = fmaf(h2[d], Wc[d * CLS + tid], s);
        lg[tid] = s;
    }
    __syncthreads();
    if (tid == 0) {   // log_softmax over 14 classes
        float m = lg[0];
        for (int j = 1; j < CLS; ++j) m = fmaxf(m, lg[j]);
        float ssum = 0.0f;
        for (int j = 0; j < CLS; ++j) ssum += expf(lg[j] - m);
        red[0] = m;
        red[1] = logf(ssum);
    }
    __syncthreads();
    if (tid < CLS) out[(size_t)b * CLS + tid] = lg[tid] - red[0] - red[1];
}

extern "C" void kernel_launch(void* const* d_in, const int* in_sizes, int n_in,
                              void* d_out, int out_size, void* d_ws, size_t ws_size,
                              hipStream_t stream) {
    const float* x   = (const float*)d_in[0];
    // d_in[1] = batch (int64) — unused by the computation
    const float* W1  = (const float*)d_in[2];
    const float* b1  = (const float*)d_in[3];
    const float* g1  = (const float*)d_in[4];
    const float* be1 = (const float*)d_in[5];
    const float* Wa  = (const float*)d_in[6];
    const float* ba  = (const float*)d_in[7];
    const float* ga  = (const float*)d_in[8];
    const float* bea = (const float*)d_in[9];
    const float* Wb  = (const float*)d_in[10];
    const float* bb  = (const float*)d_in[11];
    const float* gb  = (const float*)d_in[12];
    const float* beb = (const float*)d_in[13];
    const float* Wc  = (const float*)d_in[14];
    const float* bc  = (const float*)d_in[15];
    float* out = (float*)d_out;
    float* acc = (float*)d_ws;      // [B,448] accumulator

    hipMemsetAsync(acc, 0, (size_t)BB * 448 * sizeof(float), stream);

    dim3 grid(16, BB, 7);
    knn_edge_kernel<<<grid, 256, 0, stream>>>(x, W1, b1, g1, be1, acc);
    head_kernel<<<BB, 512, 0, stream>>>(acc, Wa, ba, ga, bea,
                                        Wb, bb, gb, beb, Wc, bc, out);
}

// Round 4
// 318.990 us; speedup vs baseline: 1.9152x; 1.9152x over previous
//
#include <hip/hip_runtime.h>

#define BB 32
#define TT 8
#define NN 1024
#define KNN 20
#define HH 64
#define CLS 14

__device__ __constant__ float kEPS = 1e-5f;

// Exact iterative extraction fallback (survivor-buffer overflow only).
__device__ __forceinline__ void fallback20(unsigned fd[16], int lane, unsigned* nb) {
    for (int kk = 0; kk < KNN; ++kk) {
        unsigned bv = fd[0];
        int bi = 0;
        #pragma unroll
        for (int i = 1; i < 16; ++i)
            if (fd[i] < bv) { bv = fd[i]; bi = i; }
        unsigned bj = (unsigned)(bi * 64 + lane);
        #pragma unroll
        for (int off = 32; off >= 1; off >>= 1) {
            const unsigned ov = __shfl_xor(bv, off, 64);
            const unsigned oj = __shfl_xor(bj, off, 64);
            if (ov < bv || (ov == bv && oj < bj)) { bv = ov; bj = oj; }
        }
        if (lane == 0) nb[kk] = bj;
        #pragma unroll
        for (int i = 0; i < 16; ++i)
            if (bj == (unsigned)(i * 64 + lane)) fd[i] = 0xFFFFFFFFu;
    }
}

// ---------------------------------------------------------------------------
// Kernel A: per (t, b, 64-point chunk). One wave = 16 query points, one at a
// time (low VGPR -> occupancy). Per point:
//   distances (flipped-uint) -> per-lane min -> 12-step ballot radix on the
//   64 lane-mins gives UB >= true d(20) -> ballot-compact survivors (<=~24
//   expected) into LDS, one per lane -> 32-step ballot radix-select over
//   survivor lanes = EXACT v20 (no shuffle network anywhere) -> ballot
//   selection of {fd < v20} U lowest-index ties = exact jax top-20 set ->
//   EdgeConv MLP (lane = channel), clamp at 0 folded into running max,
//   uint atomicMax into acc.
// ---------------------------------------------------------------------------
__global__ __launch_bounds__(256, 4) void knn_edge_kernel(
    const float* __restrict__ x,    // [B,T,N,3]
    const float* __restrict__ W1,   // [6,H]
    const float* __restrict__ b1,   // [H]
    const float* __restrict__ g1,   // [H]
    const float* __restrict__ be1,  // [H]
    float* __restrict__ acc)        // [B, 7*H], zero-initialized
{
    __shared__ float4 pts[NN];                      // x, y, z, |p|^2
    __shared__ unsigned long long keybuf[4][64];    // per-wave survivor keys
    __shared__ unsigned nbuf[4][KNN];               // per-wave neighbor indices
    __shared__ unsigned smax[HH];

    const int chunk = blockIdx.x;   // 0..15
    const int b     = blockIdx.y;   // 0..31
    const int t     = blockIdx.z;   // 0..6

    const int tid  = threadIdx.x;
    const int lane = tid & 63;
    const int wave = tid >> 6;

    for (int i = tid; i < NN; i += 256) {
        const float* p = x + (((size_t)b * TT + t) * NN + i) * 3;
        const float px = p[0], py = p[1], pz = p[2];
        pts[i] = make_float4(px, py, pz, px * px + py * py + pz * pz);
    }
    if (tid < HH) smax[tid] = 0u;
    __syncthreads();

    const float w0 = W1[0 * HH + lane], w1 = W1[1 * HH + lane],
                w2 = W1[2 * HH + lane], w3 = W1[3 * HH + lane],
                w4 = W1[4 * HH + lane], w5 = W1[5 * HH + lane];
    const float w03 = w0 - w3, w14 = w1 - w4, w25 = w2 - w5;
    const float b1l   = b1[lane];
    const float scale = g1[lane] / sqrtf(1.0f + kEPS);
    const float be1l  = be1[lane];

    const unsigned long long below = (1ull << lane) - 1ull;
    float cmax = 0.0f;

    const int n0 = chunk * 64 + wave * 16;
    for (int p = 0; p < 16; ++p) {
        const int n = n0 + p;
        const float* c = x + (((size_t)b * TT + (t + 1)) * NN + n) * 3;
        const float cx = c[0], cy = c[1], cz = c[2];
        const float s1 = cx * cx + cy * cy + cz * cz;
        const float n2x = -2.0f * cx, n2y = -2.0f * cy, n2z = -2.0f * cz;

        // distances as order-preserving flipped uints + per-lane min
        unsigned fd[16];
        unsigned mn = 0xFFFFFFFFu;
        #pragma unroll
        for (int i = 0; i < 16; ++i) {
            const float4 q = pts[i * 64 + lane];
            const float dd = fmaf(n2x, q.x, fmaf(n2y, q.y, fmaf(n2z, q.z, s1 + q.w)));
            unsigned u = __float_as_uint(dd);
            u ^= (unsigned)((int)u >> 31) | 0x80000000u;
            fd[i] = u;
            mn = min(mn, u);
        }

        // 12-step ballot radix on lane-mins: UB >= 20th lane-min >= d(20)
        unsigned pp = 0;
        int krem = 19;
        #pragma unroll
        for (int bit = 31; bit >= 20; --bit) {
            const unsigned long long z = __ballot(((mn ^ pp) >> bit) == 0u);
            const int c0 = (int)__popcll(z);
            if (krem >= c0) { pp |= (1u << bit); krem -= c0; }
        }
        const unsigned ub = pp | 0xFFFFFu;

        // ballot-compact survivors (fd <= ub) into per-wave LDS key buffer
        int base = 0;
        #pragma unroll
        for (int i = 0; i < 16; ++i) {
            const bool pr = fd[i] <= ub;
            const unsigned long long mk = __ballot(pr);
            if (pr) {
                const int pos = base + (int)__popcll(mk & below);
                if (pos < 64) keybuf[wave][pos] =
                    ((unsigned long long)fd[i] << 32) | (unsigned)(i * 64 + lane);
            }
            base += (int)__popcll(mk);
        }

        if (base <= 64) {
            const unsigned long long key = keybuf[wave][lane];
            const bool valid = lane < base;
            const unsigned sfd = valid ? (unsigned)(key >> 32) : 0xFFFFFFFFu;
            const unsigned sidx = (unsigned)key & 1023u;

            // exact v20 (rank-19 survivor value) via 32-step ballot radix-select
            unsigned v20 = 0;
            int k2 = 19;
            #pragma unroll
            for (int bit = 31; bit >= 0; --bit) {
                const unsigned long long z = __ballot(valid && ((sfd ^ v20) >> bit) == 0u);
                const int c0 = (int)__popcll(z);
                if (k2 >= c0) { v20 |= (1u << bit); k2 -= c0; }
            }

            // exact top-20 set: {fd < v20} U lowest-index ties at v20
            const unsigned long long ltm = __ballot(valid && sfd < v20);
            const int need = KNN - (int)__popcll(ltm);
            const unsigned long long tiedm = __ballot(valid && sfd == v20);
            bool sel;
            if ((int)__popcll(tiedm) == need) {
                sel = valid && sfd <= v20;
            } else {
                int r = 0;
                unsigned long long mm = tiedm;
                while (mm) {
                    const int l = __builtin_ctzll(mm);
                    const unsigned oi = __shfl(sidx, l, 64);
                    r += (oi < sidx) ? 1 : 0;
                    mm &= mm - 1;
                }
                sel = valid && (sfd < v20 || (sfd == v20 && r < need));
            }
            const unsigned long long sm = __ballot(sel);
            if (sel) nbuf[wave][(int)__popcll(sm & below)] = sidx;
        } else {
            fallback20(fd, lane, &nbuf[wave][0]);
        }

        // EdgeConv MLP, lane = channel; algebra folded:
        // h = [b + c·(w3,w4,w5)] + n·(w0-w3, w1-w4, w2-w5)
        const float mb = fmaf(cx, w3, fmaf(cy, w4, fmaf(cz, w5, b1l)));
        #pragma unroll
        for (int kk = 0; kk < KNN; ++kk) {
            const int j = (int)nbuf[wave][kk];     // uniform -> LDS broadcast
            const float4 q = pts[j];
            float h = fmaf(q.x, w03, fmaf(q.y, w14, fmaf(q.z, w25, mb)));
            h = fmaxf(h, 0.0f);
            h = fmaf(h, scale, be1l);
            cmax = fmaxf(cmax, h);
        }
    }

    atomicMax(&smax[lane], __float_as_uint(cmax));
    __syncthreads();
    if (tid < HH) {
        unsigned* dst = (unsigned*)(acc + ((size_t)b * 448 + t * 64 + tid));
        atomicMax(dst, smax[tid]);
    }
}

// ---------------------------------------------------------------------------
// Kernel B: MLP head, one block (512 threads) per batch row.
// ---------------------------------------------------------------------------
__global__ __launch_bounds__(512) void head_kernel(
    const float* __restrict__ acc,  // [B,448]
    const float* __restrict__ Wa, const float* __restrict__ ba,
    const float* __restrict__ ga, const float* __restrict__ bea,
    const float* __restrict__ Wb, const float* __restrict__ bb,
    const float* __restrict__ gb, const float* __restrict__ beb,
    const float* __restrict__ Wc, const float* __restrict__ bc,
    float* __restrict__ out)        // [B,CLS]
{
    __shared__ float s0[448];
    __shared__ float h1[512];
    __shared__ float h2[256];
    __shared__ float lg[CLS];
    __shared__ float red[2];

    const int b   = blockIdx.x;
    const int tid = threadIdx.x;
    const float inv = 1.0f / sqrtf(1.0f + kEPS);

    if (tid < 448) s0[tid] = acc[(size_t)b * 448 + tid];
    __syncthreads();

    {   // layer a: 448 -> 512
        float s = ba[tid];
        for (int d = 0; d < 448; ++d) s = fmaf(s0[d], Wa[d * 512 + tid], s);
        s = fmaxf(s, 0.0f);
        h1[tid] = fmaf(s, ga[tid] * inv, bea[tid]);
    }
    __syncthreads();
    if (tid < 256) {  // layer b: 512 -> 256
        float s = bb[tid];
        for (int d = 0; d < 512; ++d) s = fmaf(h1[d], Wb[d * 256 + tid], s);
        s = fmaxf(s, 0.0f);
        h2[tid] = fmaf(s, gb[tid] * inv, beb[tid]);
    }
    __syncthreads();
    if (tid < CLS) {  // logits: 256 -> 14
        float s = bc[tid];
        for (int d = 0; d < 256; ++d) s = fmaf(h2[d], Wc[d * CLS + tid], s);
        lg[tid] = s;
    }
    __syncthreads();
    if (tid == 0) {   // log_softmax over 14 classes
        float m = lg[0];
        for (int j = 1; j < CLS; ++j) m = fmaxf(m, lg[j]);
        float ssum = 0.0f;
        for (int j = 0; j < CLS; ++j) ssum += expf(lg[j] - m);
        red[0] = m;
        red[1] = logf(ssum);
    }
    __syncthreads();
    if (tid < CLS) out[(size_t)b * CLS + tid] = lg[tid] - red[0] - red[1];
}

extern "C" void kernel_launch(void* const* d_in, const int* in_sizes, int n_in,
                              void* d_out, int out_size, void* d_ws, size_t ws_size,
                              hipStream_t stream) {
    const float* x   = (const float*)d_in[0];
    // d_in[1] = batch (int64) — unused by the computation
    const float* W1  = (const float*)d_in[2];
    const float* b1  = (const float*)d_in[3];
    const float* g1  = (const float*)d_in[4];
    const float* be1 = (const float*)d_in[5];
    const float* Wa  = (const float*)d_in[6];
    const float* ba  = (const float*)d_in[7];
    const float* ga  = (const float*)d_in[8];
    const float* bea = (const float*)d_in[9];
    const float* Wb  = (const float*)d_in[10];
    const float* bb  = (const float*)d_in[11];
    const float* gb  = (const float*)d_in[12];
    const float* beb = (const float*)d_in[13];
    const float* Wc  = (const float*)d_in[14];
    const float* bc  = (const float*)d_in[15];
    float* out = (float*)d_out;
    float* acc = (float*)d_ws;      // [B,448] accumulator

    hipMemsetAsync(acc, 0, (size_t)BB * 448 * sizeof(float), stream);

    dim3 grid(16, BB, 7);
    knn_edge_kernel<<<grid, 256, 0, stream>>>(x, W1, b1, g1, be1, acc);
    head_kernel<<<BB, 512, 0, stream>>>(acc, Wa, ba, ga, bea,
                                        Wb, bb, gb, beb, Wc, bc, out);
}